// Round 2
// baseline (110.348 us; speedup 1.0000x reference)
//
#include <hip/hip_runtime.h>

#define NBINS 128
#define DCOLS 512
#define NCOPY 8      // banked u/v copies to cut atomic contention
#define GRID  512    // 2 blocks/CU

// ws layout (bytes):
//   [0, 16384)        float ubank[8][512]
//   [16384, 32768)    float vbank[8][512]
//   [32768, 32780)    float scal[3]  (T, P, Q)
//   [32784, 32788)    int ticket
// memset range: [0, 32800)

__global__ __launch_bounds__(256) void fused_kernel(
    const float* __restrict__ x, const int* __restrict__ tgt, int n, int d,
    float* __restrict__ ubank, float* __restrict__ vbank,
    float* __restrict__ scal, int* __restrict__ ticket,
    float* __restrict__ out)
{
    const int tid = threadIdx.x;
    __shared__ int   h[NBINS];
    __shared__ float ush[DCOLS];
    __shared__ float vsh[DCOLS];
    __shared__ float red[3][4];
    __shared__ float red2[4][4];
    __shared__ int   amlast;

    // ---- phase 1: redundant per-block histogram (targets are 32 KB, L2-hot) ----
    if (tid < NBINS) h[tid] = 0;
    __syncthreads();
    for (int i = tid; i < n; i += 256)
        atomicAdd(&h[tgt[i] & (NBINS - 1)], 1);
    __syncthreads();

    // ---- phase 2: grid-stride main pass over rows ----
    const int half = tid >> 7;     // which row of the pair this thread works on
    const int j    = tid & 127;    // float4 column group (128*4 = 512 cols)
    float t_acc = 0.f, p_acc = 0.f, q_acc = 0.f;
    float4 ua = make_float4(0.f, 0.f, 0.f, 0.f);
    float4 va = make_float4(0.f, 0.f, 0.f, 0.f);

    for (int row = blockIdx.x * 2 + half; row < n; row += gridDim.x * 2) {
        float c = (float)h[tgt[row] & (NBINS - 1)];
        float4 xv = ((const float4*)(x + (size_t)row * DCOLS))[j];
        float sq = xv.x * xv.x + xv.y * xv.y + xv.z * xv.z + xv.w * xv.w;
        float sm = xv.x + xv.y + xv.z + xv.w;
        t_acc += sq;
        p_acc += c * sq;
        q_acc += c * sm;
        ua.x += xv.x;     ua.y += xv.y;     ua.z += xv.z;     ua.w += xv.w;
        va.x += c * xv.x; va.y += c * xv.y; va.z += c * xv.z; va.w += c * xv.w;
    }

    // ---- u/v block reduction (half 0 writes, half 1 adds) ----
    if (half == 0) {
        ush[4*j+0] = ua.x; ush[4*j+1] = ua.y; ush[4*j+2] = ua.z; ush[4*j+3] = ua.w;
        vsh[4*j+0] = va.x; vsh[4*j+1] = va.y; vsh[4*j+2] = va.z; vsh[4*j+3] = va.w;
    }
    __syncthreads();
    if (half == 1) {
        ush[4*j+0] += ua.x; ush[4*j+1] += ua.y; ush[4*j+2] += ua.z; ush[4*j+3] += ua.w;
        vsh[4*j+0] += va.x; vsh[4*j+1] += va.y; vsh[4*j+2] += va.z; vsh[4*j+3] += va.w;
    }
    __syncthreads();

    // ---- banked global accumulation: hardware fp32 atomics, 64 per address ----
    {
        const int cb = (blockIdx.x & (NCOPY - 1)) * DCOLS;
        unsafeAtomicAdd(&ubank[cb + 2*tid + 0], ush[2*tid + 0]);
        unsafeAtomicAdd(&ubank[cb + 2*tid + 1], ush[2*tid + 1]);
        unsafeAtomicAdd(&vbank[cb + 2*tid + 0], vsh[2*tid + 0]);
        unsafeAtomicAdd(&vbank[cb + 2*tid + 1], vsh[2*tid + 1]);
    }

    // ---- scalar (T,P,Q) reduction ----
    for (int off = 32; off > 0; off >>= 1) {
        t_acc += __shfl_down(t_acc, off);
        p_acc += __shfl_down(p_acc, off);
        q_acc += __shfl_down(q_acc, off);
    }
    const int wave = tid >> 6, lane = tid & 63;
    if (lane == 0) { red[0][wave] = t_acc; red[1][wave] = p_acc; red[2][wave] = q_acc; }
    __syncthreads();
    if (tid == 0) {
        unsafeAtomicAdd(&scal[0], red[0][0] + red[0][1] + red[0][2] + red[0][3]);
        unsafeAtomicAdd(&scal[1], red[1][0] + red[1][1] + red[1][2] + red[1][3]);
        unsafeAtomicAdd(&scal[2], red[2][0] + red[2][1] + red[2][2] + red[2][3]);
    }

    // ---- ticket: last block to finish does the finalize ----
    __threadfence();
    __syncthreads();
    if (tid == 0)
        amlast = (atomicAdd(ticket, 1) == (int)gridDim.x - 1);
    __syncthreads();
    if (!amlast) return;
    __threadfence();

    // ---- final: column sums over banks -> UU, US, UV; WC from LDS hist ----
    float uu = 0.f, us = 0.f, uv = 0.f, wc = 0.f;
    for (int k = tid; k < DCOLS; k += 256) {
        float uf = 0.f, vf = 0.f;
        #pragma unroll
        for (int cpy = 0; cpy < NCOPY; ++cpy) {
            uf += __hip_atomic_load(&ubank[cpy*DCOLS + k], __ATOMIC_RELAXED, __HIP_MEMORY_SCOPE_AGENT);
            vf += __hip_atomic_load(&vbank[cpy*DCOLS + k], __ATOMIC_RELAXED, __HIP_MEMORY_SCOPE_AGENT);
        }
        uu += uf * uf;
        us += uf;
        uv += uf * vf;
    }
    if (tid < NBINS) { float hh = (float)h[tid]; wc = hh * hh; }

    for (int off = 32; off > 0; off >>= 1) {
        uu += __shfl_down(uu, off);
        us += __shfl_down(us, off);
        uv += __shfl_down(uv, off);
        wc += __shfl_down(wc, off);
    }
    if (lane == 0) { red2[0][wave] = uu; red2[1][wave] = us; red2[2][wave] = uv; red2[3][wave] = wc; }
    __syncthreads();
    if (tid == 0) {
        double UU = 0, US = 0, UV = 0, WC = 0;
        for (int w = 0; w < 4; ++w) {
            UU += red2[0][w]; US += red2[1][w]; UV += red2[2][w]; WC += red2[3][w];
        }
        const double T = __hip_atomic_load(&scal[0], __ATOMIC_RELAXED, __HIP_MEMORY_SCOPE_AGENT);
        const double P = __hip_atomic_load(&scal[1], __ATOMIC_RELAXED, __HIP_MEMORY_SCOPE_AGENT);
        const double Q = __hip_atomic_load(&scal[2], __ATOMIC_RELAXED, __HIP_MEMORY_SCOPE_AGENT);
        const double N = (double)n, Dd = (double)d, eps = 1e-6;
        double Ssum = 2.0 * N * T - 2.0 * UU + N * N * Dd * eps * eps;
        double Anum = N * P + T * WC - 2.0 * UV
                    + 2.0 * eps * (N * Q - US * WC) + N * Dd * eps * eps * WC;
        double a = Anum / (N * WC);
        double b = (N * Ssum - Anum) / (N * (N * N - WC));
        out[0] = (float)(-a / b - b / a);
    }
}

extern "C" void kernel_launch(void* const* d_in, const int* in_sizes, int n_in,
                              void* d_out, int out_size, void* d_ws, size_t ws_size,
                              hipStream_t stream) {
    const float* x   = (const float*)d_in[0];
    const int*   tgt = (const int*)d_in[1];
    float*       out = (float*)d_out;

    const int n = in_sizes[1];          // 8192
    const int d = in_sizes[0] / n;      // 512

    char*  ws     = (char*)d_ws;
    float* ubank  = (float*)ws;                                  // 16 KB
    float* vbank  = (float*)(ws + NCOPY * DCOLS * 4);            // 16 KB
    float* scal   = (float*)(ws + 2 * NCOPY * DCOLS * 4);        // 12 B
    int*   ticket = (int*)  (ws + 2 * NCOPY * DCOLS * 4 + 16);   // 4 B

    hipMemsetAsync(d_ws, 0, 2 * NCOPY * DCOLS * 4 + 32, stream);
    fused_kernel<<<GRID, 256, 0, stream>>>(x, tgt, n, d, ubank, vbank, scal, ticket, out);
}

// Round 3
// 106.340 us; speedup vs baseline: 1.0377x; 1.0377x over previous
//
#include <hip/hip_runtime.h>

#define NBINS 128
#define DCOLS 512
#define NBANK 16
#define GRID  512

// ws layout (bytes):
//   [0, 32768)      float ubank[16][512]   (banked column sums of x)
//   [32768, 33280)  int   hist[128]
//   [33280, 33296)  float scal[4]          (T, P, Q, UV)
// memset range: [0, 33296)

// ---------------- pass 1: histogram + column sums u ----------------
__global__ __launch_bounds__(256) void pass1(const float* __restrict__ x,
                                             const int* __restrict__ tgt,
                                             int n,
                                             float* __restrict__ ubank,
                                             int* __restrict__ hist) {
    const int tid  = threadIdx.x;
    const int j    = tid & 127;   // float4 column group
    const int half = tid >> 7;    // row parity within block

    // histogram: first ceil(n/256) blocks each cover 256 targets
    {
        int g = blockIdx.x * 256 + tid;
        if (g < n) atomicAdd(&hist[tgt[g] & (NBINS - 1)], 1);
    }

    float4 ua = make_float4(0.f, 0.f, 0.f, 0.f);
    #pragma unroll 4
    for (int row = blockIdx.x * 2 + half; row < n; row += GRID * 2) {
        float4 xv = ((const float4*)(x + (size_t)row * DCOLS))[j];
        ua.x += xv.x; ua.y += xv.y; ua.z += xv.z; ua.w += xv.w;
    }

    // block-reduce the two halves (identical column ownership)
    __shared__ float ush[DCOLS];
    if (half == 0) {
        ush[4*j+0] = ua.x; ush[4*j+1] = ua.y; ush[4*j+2] = ua.z; ush[4*j+3] = ua.w;
    }
    __syncthreads();
    if (half == 1) {
        ush[4*j+0] += ua.x; ush[4*j+1] += ua.y; ush[4*j+2] += ua.z; ush[4*j+3] += ua.w;
    }
    __syncthreads();

    // banked HW fp32 atomics: 512/NBANK = 32 adds per address
    const int cb = (blockIdx.x & (NBANK - 1)) * DCOLS;
    unsafeAtomicAdd(&ubank[cb + 2*tid + 0], ush[2*tid + 0]);
    unsafeAtomicAdd(&ubank[cb + 2*tid + 1], ush[2*tid + 1]);
}

// ---------------- pass 2: T, P, Q, UV scalars ----------------
__global__ __launch_bounds__(256) void pass2(const float* __restrict__ x,
                                             const int* __restrict__ tgt,
                                             const int* __restrict__ hist,
                                             const float* __restrict__ ubank,
                                             int n,
                                             float* __restrict__ scal) {
    const int tid  = threadIdx.x;
    const int j    = tid & 127;
    const int half = tid >> 7;

    __shared__ float hl[NBINS];
    if (tid < NBINS) hl[tid] = (float)hist[tid];

    // this thread's 4-column slice of u, summed over banks (L2-hot)
    float4 uvec = make_float4(0.f, 0.f, 0.f, 0.f);
    #pragma unroll
    for (int b = 0; b < NBANK; ++b) {
        float4 t = ((const float4*)(ubank + b * DCOLS))[j];
        uvec.x += t.x; uvec.y += t.y; uvec.z += t.z; uvec.w += t.w;
    }
    __syncthreads();

    float t_acc = 0.f, p_acc = 0.f, q_acc = 0.f, uv_acc = 0.f;
    #pragma unroll 4
    for (int row = blockIdx.x * 2 + half; row < n; row += GRID * 2) {
        float c = hl[tgt[row] & (NBINS - 1)];
        float4 xv = ((const float4*)(x + (size_t)row * DCOLS))[j];
        float sq = xv.x*xv.x + xv.y*xv.y + xv.z*xv.z + xv.w*xv.w;
        float sm = xv.x + xv.y + xv.z + xv.w;
        float gd = xv.x*uvec.x + xv.y*uvec.y + xv.z*uvec.z + xv.w*uvec.w;
        t_acc  += sq;
        p_acc  += c * sq;
        q_acc  += c * sm;
        uv_acc += c * gd;
    }

    // 64-lane shuffle reduce, then cross-wave LDS, then 4 scalar atomics
    for (int off = 32; off > 0; off >>= 1) {
        t_acc  += __shfl_down(t_acc,  off);
        p_acc  += __shfl_down(p_acc,  off);
        q_acc  += __shfl_down(q_acc,  off);
        uv_acc += __shfl_down(uv_acc, off);
    }
    __shared__ float red[4][4];
    const int wave = tid >> 6, lane = tid & 63;
    if (lane == 0) {
        red[0][wave] = t_acc; red[1][wave] = p_acc;
        red[2][wave] = q_acc; red[3][wave] = uv_acc;
    }
    __syncthreads();
    if (tid == 0) {
        unsafeAtomicAdd(&scal[0], red[0][0] + red[0][1] + red[0][2] + red[0][3]);
        unsafeAtomicAdd(&scal[1], red[1][0] + red[1][1] + red[1][2] + red[1][3]);
        unsafeAtomicAdd(&scal[2], red[2][0] + red[2][1] + red[2][2] + red[2][3]);
        unsafeAtomicAdd(&scal[3], red[3][0] + red[3][1] + red[3][2] + red[3][3]);
    }
}

// ---------------- final: UU, US, WC + closed form ----------------
__global__ __launch_bounds__(256) void finalk(const int* __restrict__ hist,
                                              const float* __restrict__ scal,
                                              const float* __restrict__ ubank,
                                              int n, int d,
                                              float* __restrict__ out) {
    const int tid = threadIdx.x;
    float uu = 0.f, us = 0.f, wc = 0.f;
    for (int k = tid; k < DCOLS; k += 256) {
        float uf = 0.f;
        #pragma unroll
        for (int b = 0; b < NBANK; ++b) uf += ubank[b * DCOLS + k];
        uu += uf * uf;
        us += uf;
    }
    if (tid < NBINS) { float h = (float)hist[tid]; wc = h * h; }

    for (int off = 32; off > 0; off >>= 1) {
        uu += __shfl_down(uu, off);
        us += __shfl_down(us, off);
        wc += __shfl_down(wc, off);
    }
    __shared__ float red[3][4];
    const int wave = tid >> 6, lane = tid & 63;
    if (lane == 0) { red[0][wave] = uu; red[1][wave] = us; red[2][wave] = wc; }
    __syncthreads();
    if (tid == 0) {
        double UU = 0, US = 0, WC = 0;
        for (int w = 0; w < 4; ++w) { UU += red[0][w]; US += red[1][w]; WC += red[2][w]; }
        const double T = scal[0], P = scal[1], Q = scal[2], UV = scal[3];
        const double N = (double)n, Dd = (double)d, eps = 1e-6;
        double Ssum = 2.0 * N * T - 2.0 * UU + N * N * Dd * eps * eps;
        double Anum = N * P + T * WC - 2.0 * UV
                    + 2.0 * eps * (N * Q - US * WC) + N * Dd * eps * eps * WC;
        double a = Anum / (N * WC);
        double b = (N * Ssum - Anum) / (N * (N * N - WC));
        out[0] = (float)(-a / b - b / a);
    }
}

extern "C" void kernel_launch(void* const* d_in, const int* in_sizes, int n_in,
                              void* d_out, int out_size, void* d_ws, size_t ws_size,
                              hipStream_t stream) {
    const float* x   = (const float*)d_in[0];
    const int*   tgt = (const int*)d_in[1];
    float*       out = (float*)d_out;

    const int n = in_sizes[1];          // 8192
    const int d = in_sizes[0] / n;      // 512

    char*  ws    = (char*)d_ws;
    float* ubank = (float*)ws;                          // 32 KB
    int*   hist  = (int*)  (ws + NBANK * DCOLS * 4);    // 512 B
    float* scal  = (float*)(ws + NBANK * DCOLS * 4 + NBINS * 4); // 16 B

    hipMemsetAsync(d_ws, 0, NBANK * DCOLS * 4 + NBINS * 4 + 16, stream);

    pass1 <<<GRID, 256, 0, stream>>>(x, tgt, n, ubank, hist);
    pass2 <<<GRID, 256, 0, stream>>>(x, tgt, hist, ubank, n, scal);
    finalk<<<1,    256, 0, stream>>>(hist, scal, ubank, n, d, out);
}

// Round 4
// 89.820 us; speedup vs baseline: 1.2285x; 1.1839x over previous
//
#include <hip/hip_runtime.h>

#define NBINS 128
#define DCOLS 512
#define NBANK 16
#define RPB   16    // rows per block (one-shot)
#define F4PT  8     // float4 loads per thread

// ws layout (bytes):
//   [0, 32768)      float ubank[16][512]
//   [32768, 65536)  float vbank[16][512]
//   [65536, 66048)  int   hist[128]
//   [66048, 66064)  float scal[4]   (T, P, Q)
// memset range: [0, 66064)

// ---------------- kernel 1: histogram of targets ----------------
__global__ __launch_bounds__(256) void hist_kernel(const int* __restrict__ tgt,
                                                   int n, int* __restrict__ hist) {
    __shared__ int h[NBINS];
    const int tid = threadIdx.x;
    if (tid < NBINS) h[tid] = 0;
    __syncthreads();
    int i = blockIdx.x * 256 + tid;
    if (i < n) atomicAdd(&h[tgt[i] & (NBINS - 1)], 1);
    __syncthreads();
    if (tid < NBINS) {
        int v = h[tid];
        if (v) atomicAdd(&hist[tid], v);
    }
}

// ---------------- kernel 2: one-shot main pass ----------------
// Block b owns rows [b*16, b*16+16) = 2048 float4s; thread loads 8 float4s
// at stride 256 (all independent, issued before any dependent op).
__global__ __launch_bounds__(256) void main_pass(const float* __restrict__ x,
                                                 const int* __restrict__ tgt,
                                                 const int* __restrict__ hist,
                                                 float* __restrict__ ubank,
                                                 float* __restrict__ vbank,
                                                 float* __restrict__ scal) {
    const int tid  = threadIdx.x;
    const int half = tid >> 7;     // row parity: f4 index & bit7
    const size_t base = (size_t)blockIdx.x * (RPB * DCOLS / 4);
    const float4* xf4 = (const float4*)x;

    // ---- issue all 8 independent loads first (MLP) ----
    float4 xv[F4PT];
    #pragma unroll
    for (int k = 0; k < F4PT; ++k)
        xv[k] = xf4[base + k * 256 + tid];

    // ---- per-row class counts into LDS (overlaps with x loads) ----
    __shared__ float crow[RPB];
    if (tid < RPB)
        crow[tid] = (float)hist[tgt[blockIdx.x * RPB + tid] & (NBINS - 1)];
    __syncthreads();

    // ---- accumulate: row(k) = b*16 + 2k + half, cols = (tid&127)*4 .. +3 ----
    float t_acc = 0.f, p_acc = 0.f, q_acc = 0.f;
    float4 ua = make_float4(0.f, 0.f, 0.f, 0.f);
    float4 va = make_float4(0.f, 0.f, 0.f, 0.f);
    #pragma unroll
    for (int k = 0; k < F4PT; ++k) {
        float  c = crow[2 * k + half];
        float4 v = xv[k];
        float sq = v.x*v.x + v.y*v.y + v.z*v.z + v.w*v.w;
        float sm = v.x + v.y + v.z + v.w;
        t_acc += sq;
        p_acc += c * sq;
        q_acc += c * sm;
        ua.x += v.x;     ua.y += v.y;     ua.z += v.z;     ua.w += v.w;
        va.x += c * v.x; va.y += c * v.y; va.z += c * v.z; va.w += c * v.w;
    }

    // ---- u/v block reduction across the two halves ----
    const int j = tid & 127;
    __shared__ float ush[DCOLS];
    __shared__ float vsh[DCOLS];
    if (half == 0) {
        ush[4*j+0] = ua.x; ush[4*j+1] = ua.y; ush[4*j+2] = ua.z; ush[4*j+3] = ua.w;
        vsh[4*j+0] = va.x; vsh[4*j+1] = va.y; vsh[4*j+2] = va.z; vsh[4*j+3] = va.w;
    }
    __syncthreads();
    if (half == 1) {
        ush[4*j+0] += ua.x; ush[4*j+1] += ua.y; ush[4*j+2] += ua.z; ush[4*j+3] += ua.w;
        vsh[4*j+0] += va.x; vsh[4*j+1] += va.y; vsh[4*j+2] += va.z; vsh[4*j+3] += va.w;
    }
    __syncthreads();

    // ---- banked HW fp32 atomics: 512/NBANK = 32 adds per address ----
    const int cb = (blockIdx.x & (NBANK - 1)) * DCOLS;
    unsafeAtomicAdd(&ubank[cb + 2*tid + 0], ush[2*tid + 0]);
    unsafeAtomicAdd(&ubank[cb + 2*tid + 1], ush[2*tid + 1]);
    unsafeAtomicAdd(&vbank[cb + 2*tid + 0], vsh[2*tid + 0]);
    unsafeAtomicAdd(&vbank[cb + 2*tid + 1], vsh[2*tid + 1]);

    // ---- scalar (T,P,Q) reduction ----
    for (int off = 32; off > 0; off >>= 1) {
        t_acc += __shfl_down(t_acc, off);
        p_acc += __shfl_down(p_acc, off);
        q_acc += __shfl_down(q_acc, off);
    }
    __shared__ float red[3][4];
    const int wave = tid >> 6, lane = tid & 63;
    if (lane == 0) { red[0][wave] = t_acc; red[1][wave] = p_acc; red[2][wave] = q_acc; }
    __syncthreads();
    if (tid == 0) {
        unsafeAtomicAdd(&scal[0], red[0][0] + red[0][1] + red[0][2] + red[0][3]);
        unsafeAtomicAdd(&scal[1], red[1][0] + red[1][1] + red[1][2] + red[1][3]);
        unsafeAtomicAdd(&scal[2], red[2][0] + red[2][1] + red[2][2] + red[2][3]);
    }
}

// ---------------- kernel 3: UU, US, UV, WC + closed form ----------------
__global__ __launch_bounds__(256) void finalk(const int* __restrict__ hist,
                                              const float* __restrict__ scal,
                                              const float* __restrict__ ubank,
                                              const float* __restrict__ vbank,
                                              int n, int d,
                                              float* __restrict__ out) {
    const int tid = threadIdx.x;
    float uu = 0.f, us = 0.f, uv = 0.f, wc = 0.f;
    for (int k = tid; k < DCOLS; k += 256) {
        float uf = 0.f, vf = 0.f;
        #pragma unroll
        for (int b = 0; b < NBANK; ++b) {
            uf += ubank[b * DCOLS + k];
            vf += vbank[b * DCOLS + k];
        }
        uu += uf * uf;
        us += uf;
        uv += uf * vf;
    }
    if (tid < NBINS) { float h = (float)hist[tid]; wc = h * h; }

    for (int off = 32; off > 0; off >>= 1) {
        uu += __shfl_down(uu, off);
        us += __shfl_down(us, off);
        uv += __shfl_down(uv, off);
        wc += __shfl_down(wc, off);
    }
    __shared__ float red[4][4];
    const int wave = tid >> 6, lane = tid & 63;
    if (lane == 0) { red[0][wave] = uu; red[1][wave] = us; red[2][wave] = uv; red[3][wave] = wc; }
    __syncthreads();
    if (tid == 0) {
        double UU = 0, US = 0, UV = 0, WC = 0;
        for (int w = 0; w < 4; ++w) {
            UU += red[0][w]; US += red[1][w]; UV += red[2][w]; WC += red[3][w];
        }
        const double T = scal[0], P = scal[1], Q = scal[2];
        const double N = (double)n, Dd = (double)d, eps = 1e-6;
        double Ssum = 2.0 * N * T - 2.0 * UU + N * N * Dd * eps * eps;
        double Anum = N * P + T * WC - 2.0 * UV
                    + 2.0 * eps * (N * Q - US * WC) + N * Dd * eps * eps * WC;
        double a = Anum / (N * WC);
        double b = (N * Ssum - Anum) / (N * (N * N - WC));
        out[0] = (float)(-a / b - b / a);
    }
}

extern "C" void kernel_launch(void* const* d_in, const int* in_sizes, int n_in,
                              void* d_out, int out_size, void* d_ws, size_t ws_size,
                              hipStream_t stream) {
    const float* x   = (const float*)d_in[0];
    const int*   tgt = (const int*)d_in[1];
    float*       out = (float*)d_out;

    const int n = in_sizes[1];          // 8192
    const int d = in_sizes[0] / n;      // 512

    char*  ws    = (char*)d_ws;
    float* ubank = (float*)ws;                                   // 32 KB
    float* vbank = (float*)(ws + NBANK * DCOLS * 4);             // 32 KB
    int*   hist  = (int*)  (ws + 2 * NBANK * DCOLS * 4);         // 512 B
    float* scal  = (float*)(ws + 2 * NBANK * DCOLS * 4 + NBINS * 4); // 16 B

    hipMemsetAsync(d_ws, 0, 2 * NBANK * DCOLS * 4 + NBINS * 4 + 16, stream);

    hist_kernel<<<(n + 255) / 256, 256, 0, stream>>>(tgt, n, hist);
    main_pass  <<<n / RPB,        256, 0, stream>>>(x, tgt, hist, ubank, vbank, scal);
    finalk     <<<1,              256, 0, stream>>>(hist, scal, ubank, vbank, n, d, out);
}